// Round 13
// baseline (206.887 us; speedup 1.0000x reference)
//
#include <hip/hip_runtime.h>
#include <cstdint>
#include <cstddef>

typedef _Float16 h16;
typedef __attribute__((ext_vector_type(8))) _Float16 half8;
typedef __attribute__((ext_vector_type(4))) _Float16 half4;
typedef __attribute__((ext_vector_type(2))) _Float16 half2v;
typedef __attribute__((ext_vector_type(4))) float f32x4;
typedef __attribute__((ext_vector_type(2))) float f32x2;

#define NB 16384
#define NTAB 26
#define NR 100000

__device__ __forceinline__ void gload16(const void* g, void* l) {
  __builtin_amdgcn_global_load_lds(
      (const __attribute__((address_space(1))) unsigned int*)g,
      (__attribute__((address_space(3))) unsigned int*)l, 16, 0, 0);
}

// ---- fused: f32->fp16 weight conversion (blocks 0..9343) + bottom layer 0
// (blocks 9344..42111): Y[B,512] = relu(x @ W0^T + b0), fp16 out.
__global__ __launch_bounds__(256) void cvt_bot0_k(
    const float* __restrict__ s0, const float* __restrict__ s1,
    const float* __restrict__ s2, const float* __restrict__ s3,
    const float* __restrict__ s4, const float* __restrict__ s5,
    h16* __restrict__ dst, const float* __restrict__ x,
    const float* __restrict__ W0, const float* __restrict__ b0,
    h16* __restrict__ Y) {
  int b = blockIdx.x;
  if (b >= 9344) {
    int gid = (b - 9344) * 256 + threadIdx.x;
    int row = gid >> 9;
    int n = gid & 511;
    const float* xr = x + row * 13;
    const float* wr = W0 + n * 13;
    float acc = b0[n];
#pragma unroll
    for (int k = 0; k < 13; ++k) acc += xr[k] * wr[k];
    Y[gid] = (h16)fmaxf(acc, 0.f);
    return;
  }
  const float* src; int K, kl, i0; size_t doff;
  if (b < 512)       { src=s0; K=512;  kl=9;  i0=(b-0)*256;    doff=0; }
  else if (b < 640)  { src=s1; K=256;  kl=8;  i0=(b-512)*256;  doff=131072; }
  else if (b < 2688) { src=s2; K=479;  kl=9;  i0=(b-640)*256;  doff=163840; }
  else if (b < 6784) { src=s3; K=1024; kl=10; i0=(b-2688)*256; doff=688128; }
  else if (b < 8832) { src=s4; K=1024; kl=10; i0=(b-6784)*256; doff=1736704; }
  else               { src=s5; K=512;  kl=9;  i0=(b-8832)*256; doff=2260992; }
  int i = i0 + threadIdx.x;
  int n = i >> kl, k = i & ((1 << kl) - 1);
  dst[doff + i] = (k < K) ? (h16)src[(size_t)n * K + k] : (h16)0.f;
}

// ---- fused mid MLP (R12): Xc = relu(relu(Y0 @ W1^T + b1) @ W2^T + b2).
__global__ __launch_bounds__(256, 2) void mid_k(
    const h16* __restrict__ Y0, const h16* __restrict__ W1,
    const float* __restrict__ b1, const h16* __restrict__ W2,
    const float* __restrict__ b2, h16* __restrict__ Xc) {
  __shared__ __align__(16) h16 Sa[64 * 64];
  __shared__ __align__(16) h16 Sb[256 * 64];
  __shared__ __align__(16) h16 Y1[64 * 264];
  const int tid = threadIdx.x;
  const int lane = tid & 63;
  const int w = tid >> 6;
  const int l15 = lane & 15;
  const int kq = lane >> 4;
  const int l7 = lane & 7;
  const int lr8 = lane >> 3;
  const size_t row0 = (size_t)blockIdx.x * 64;

  const int sch = (lane & 7) ^ lr8;
  const h16* gA = Y0 + (row0 + w * 16 + lr8) * 512 + sch * 8;
  const h16* gB = W1 + ((size_t)w * 64 + lr8) * 512 + sch * 8;

  f32x4 acc[4][4] = {};
  for (int t = 0; t < 8; ++t) {
    const int k0 = t * 64;
#pragma unroll
    for (int i = 0; i < 2; ++i)
      gload16(gA + (size_t)i * 8 * 512 + k0, Sa + w * 1024 + i * 512);
#pragma unroll
    for (int i = 0; i < 8; ++i)
      gload16(gB + (size_t)i * 8 * 512 + k0, Sb + w * 4096 + i * 512);
    __syncthreads();
#pragma unroll
    for (int kk = 0; kk < 2; ++kk) {
      const int kb = kk * 4 + kq;
      half8 a[4], bfr[4];
#pragma unroll
      for (int mi = 0; mi < 4; ++mi)
        a[mi] = *(const half8*)&Sa[(mi * 16 + l15) * 64 + ((kb ^ l7) << 3)];
#pragma unroll
      for (int ni = 0; ni < 4; ++ni)
        bfr[ni] = *(const half8*)&Sb[(w * 64 + ni * 16 + l15) * 64 + ((kb ^ l7) << 3)];
#pragma unroll
      for (int mi = 0; mi < 4; ++mi)
#pragma unroll
        for (int ni = 0; ni < 4; ++ni)
          acc[mi][ni] = __builtin_amdgcn_mfma_f32_16x16x32_f16(bfr[ni], a[mi], acc[mi][ni], 0, 0, 0);
    }
    __syncthreads();
  }

#pragma unroll
  for (int mi = 0; mi < 4; ++mi) {
    const int row = mi * 16 + l15;
#pragma unroll
    for (int ni = 0; ni < 4; ++ni) {
      const int col = w * 64 + ni * 16 + kq * 4;
      const f32x4 bv = *(const f32x4*)&b1[col];
      half4 h;
#pragma unroll
      for (int ri = 0; ri < 4; ++ri)
        h[ri] = (h16)fmaxf(acc[mi][ni][ri] + bv[ri], 0.f);
      *(half4*)&Y1[row * 264 + col] = h;
    }
  }
  __syncthreads();

  f32x4 acc2[4][2] = {};
  for (int ks = 0; ks < 8; ++ks) {
    half8 av[4], bv[2];
#pragma unroll
    for (int mi = 0; mi < 4; ++mi)
      av[mi] = *(const half8*)&Y1[(mi * 16 + l15) * 264 + ks * 32 + kq * 8];
#pragma unroll
    for (int nf = 0; nf < 2; ++nf) {
      const int col = (w * 2 + nf) * 16 + l15;
      bv[nf] = *(const half8*)&W2[(size_t)col * 256 + ks * 32 + kq * 8];
    }
#pragma unroll
    for (int mi = 0; mi < 4; ++mi)
#pragma unroll
      for (int nf = 0; nf < 2; ++nf)
        acc2[mi][nf] = __builtin_amdgcn_mfma_f32_16x16x32_f16(bv[nf], av[mi], acc2[mi][nf], 0, 0, 0);
  }
#pragma unroll
  for (int mi = 0; mi < 4; ++mi) {
    const size_t row = row0 + mi * 16 + l15;
#pragma unroll
    for (int nf = 0; nf < 2; ++nf) {
      const int col = (w * 2 + nf) * 16 + kq * 4;
      const f32x4 bv = *(const f32x4*)&b2[col];
      half4 h;
#pragma unroll
      for (int ri = 0; ri < 4; ++ri)
        h[ri] = (h16)fmaxf(acc2[mi][nf][ri] + bv[ri], 0.f);
      *(half4*)&Xc[row * 128 + col] = h;
    }
  }
}

// ---- WIDE-ACC 256x128-tile single-buffered fp16 MFMA GEMM (big layers).
// 4 waves (2x2), per-wave 128x64 output (acc[8][4]), BK=64, 48KB LDS.
// Fragment economy: 24 ds_read_b128 feed 64 MFMA per K-tile per wave
// (vs 16:16 in the 128^2 kernel) -> 2.67x fewer LDS bytes/FLOP, attacking
// the R10-measured LDS-BW bound (MfmaUtil 37%, 0 conflicts, HBM 16%).
// Same proven zero-conflict XOR layout; b-frags loaded once per kk,
// a-frags streamed (1 live) to keep VGPR ~170. XCD-aware decode.
// GYL = log2(N/128); grid = (M/256)*(N/128).
template <int GYL>
__global__ __launch_bounds__(256, 2) void gemm_wd(
    const h16* __restrict__ A, const h16* __restrict__ W,
    const float* __restrict__ bias, h16* __restrict__ C, int N, int K) {
  __shared__ __align__(16) h16 As[256 * 64];
  __shared__ __align__(16) h16 Bs[128 * 64];
  const int b = blockIdx.x;
  const int c8 = b & 7;
  const int q = b >> 3;
  const int jcol = q & ((1 << GYL) - 1);
  const int krow = ((q >> GYL) << 3) | c8;
  const int tid = threadIdx.x;
  const int lane = tid & 63;
  const int wave = tid >> 6;
  const int wm = wave >> 1, wn = wave & 1;
  const size_t row0 = (size_t)krow * 256;
  const size_t col0 = (size_t)jcol * 128;
  const int l15 = lane & 15;
  const int kq = lane >> 4;
  const int l7 = lane & 7;
  const int nt = K >> 6;

  // staging: thread t covers row (t>>3)+i*32, swizzled chunk (t&7)^((t>>3)&7)
  const int srow = tid >> 3;
  const int swc = ((tid & 7) ^ (srow & 7)) << 3;
  const h16* ga = A + (row0 + srow) * (size_t)K + swc;
  const h16* gb = W + (col0 + srow) * (size_t)K + swc;

  f32x4 acc[8][4] = {};

  for (int t = 0; t < nt; ++t) {
    const int k0 = t << 6;
#pragma unroll
    for (int i = 0; i < 8; ++i)
      gload16(ga + (size_t)(i * 32) * K + k0, As + i * 2048 + tid * 8);
#pragma unroll
    for (int i = 0; i < 4; ++i)
      gload16(gb + (size_t)(i * 32) * K + k0, Bs + i * 2048 + tid * 8);
    __syncthreads();
#pragma unroll
    for (int kk = 0; kk < 2; ++kk) {
      const int kb = kk * 4 + kq;
      const int sl = (kb ^ l7) << 3;
      half8 bfr[4];
#pragma unroll
      for (int ni = 0; ni < 4; ++ni)
        bfr[ni] = *(const half8*)&Bs[(wn * 64 + ni * 16 + l15) * 64 + sl];
#pragma unroll
      for (int mi = 0; mi < 8; ++mi) {
        half8 av = *(const half8*)&As[(wm * 128 + mi * 16 + l15) * 64 + sl];
#pragma unroll
        for (int ni = 0; ni < 4; ++ni)
          acc[mi][ni] = __builtin_amdgcn_mfma_f32_16x16x32_f16(av, bfr[ni], acc[mi][ni], 0, 0, 0);
      }
    }
    __syncthreads();
  }

#pragma unroll
  for (int mi = 0; mi < 8; ++mi)
#pragma unroll
    for (int ni = 0; ni < 4; ++ni) {
      const size_t col = col0 + wn * 64 + ni * 16 + l15;
      const float bv = bias[col];
#pragma unroll
      for (int ri = 0; ri < 4; ++ri) {
        const size_t row = row0 + wm * 128 + mi * 16 + kq * 4 + ri;
        float v = acc[mi][ni][ri] + bv;
        C[row * N + col] = (h16)fmaxf(v, 0.f);
      }
    }
}

// ---- T3 + top4 fused, single-buffered (N=256, K=512) (R11/R12).
__global__ __launch_bounds__(256, 4) void gemm_t3f(
    const h16* __restrict__ A, const h16* __restrict__ W,
    const float* __restrict__ bias, const float* __restrict__ w4,
    float* __restrict__ partial) {
  const int K = 512;
  __shared__ __align__(16) h16 As[128 * 64];
  __shared__ __align__(16) h16 Bs[128 * 64];
  const int b = blockIdx.x;
  const int c8 = b & 7;
  const int q = b >> 3;
  const int jcol = q & 1;
  const int krow = ((q >> 1) << 3) | c8;
  const int tid = threadIdx.x;
  const int lane = tid & 63;
  const int wave = tid >> 6;
  const int wm = wave >> 1, wn = wave & 1;
  const size_t row0 = (size_t)krow * 128;
  const size_t col0 = (size_t)jcol * 128;
  const int lr = lane >> 3;
  const int swzc = (((lane & 7) ^ lr) << 3);
  const int l15 = lane & 15;
  const int kq = lane >> 4;
  const int l7 = lane & 7;
  const int nt = K >> 6;

  const h16* ga = A + (row0 + wave * 32 + lr) * (size_t)K + swzc;
  const h16* gb = W + (col0 + wave * 32 + lr) * (size_t)K + swzc;

  f32x4 acc[4][4] = {};

  for (int t = 0; t < nt; ++t) {
    const int k0 = t << 6;
    h16* la = As + wave * 2048;
    h16* lb = Bs + wave * 2048;
#pragma unroll
    for (int i = 0; i < 4; ++i) {
      gload16(ga + (size_t)i * 8 * K + k0, la + i * 512);
      gload16(gb + (size_t)i * 8 * K + k0, lb + i * 512);
    }
    __syncthreads();
#pragma unroll
    for (int kk = 0; kk < 2; ++kk) {
      half8 a[4], bfr[4];
      const int kb = kk * 4 + kq;
#pragma unroll
      for (int mi = 0; mi < 4; ++mi)
        a[mi] = *(const half8*)&As[(wm * 64 + mi * 16 + l15) * 64 + ((kb ^ l7) << 3)];
#pragma unroll
      for (int ni = 0; ni < 4; ++ni)
        bfr[ni] = *(const half8*)&Bs[(wn * 64 + ni * 16 + l15) * 64 + ((kb ^ l7) << 3)];
#pragma unroll
      for (int mi = 0; mi < 4; ++mi)
#pragma unroll
        for (int ni = 0; ni < 4; ++ni)
          acc[mi][ni] = __builtin_amdgcn_mfma_f32_16x16x32_f16(a[mi], bfr[ni], acc[mi][ni], 0, 0, 0);
    }
    __syncthreads();
  }

  const int slot = jcol * 2 + wn;
#pragma unroll
  for (int mi = 0; mi < 4; ++mi) {
    float s[4] = {0.f, 0.f, 0.f, 0.f};
#pragma unroll
    for (int ni = 0; ni < 4; ++ni) {
      const size_t col = col0 + wn * 64 + ni * 16 + l15;
      const float bv = bias[col];
      const float wv = w4[col];
#pragma unroll
      for (int ri = 0; ri < 4; ++ri)
        s[ri] += fmaxf(acc[mi][ni][ri] + bv, 0.f) * wv;
    }
#pragma unroll
    for (int ri = 0; ri < 4; ++ri) {
      float v = s[ri];
      v += __shfl_xor(v, 1);
      v += __shfl_xor(v, 2);
      v += __shfl_xor(v, 4);
      v += __shfl_xor(v, 8);
      if (l15 == 0) {
        const size_t row = row0 + wm * 64 + mi * 16 + kq * 4 + ri;
        partial[(size_t)slot * NB + row] = v;
      }
    }
  }
}

// ---- final: out[r] = sigmoid(sum of 4 partials + tb4)
__global__ __launch_bounds__(256) void sig_k(
    const float* __restrict__ partial, const float* __restrict__ bias,
    float* __restrict__ out) {
  int r = blockIdx.x * 256 + threadIdx.x;
  float v = partial[r] + partial[NB + r] + partial[2 * NB + r] +
            partial[3 * NB + r] + bias[0];
  out[r] = 1.f / (1.f + expf(-v));
}

// ---- fused embedding gather + interaction (R9/R11).
__global__ __launch_bounds__(256) void interact_k(
    const h16* __restrict__ X, const float* __restrict__ emb,
    const int* __restrict__ lSi, h16* __restrict__ z) {
  __shared__ __align__(16) h16 T[4][32][136];
  const int lane = threadIdx.x & 63;
  const int wv = threadIdx.x >> 6;
  const size_t b = (size_t)blockIdx.x * 4 + wv;

  int idxs[NTAB];
#pragma unroll
  for (int t = 0; t < NTAB; ++t) idxs[t] = lSi[t * NB + (int)b];

  for (int i = lane; i < 5 * 128; i += 64)
    T[wv][27 + (i >> 7)][i & 127] = (h16)0.f;

  {
    half2v v = *(const half2v*)(X + b * 128 + lane * 2);
    *(half2v*)&T[wv][0][lane * 2] = v;
    *(half2v*)(z + b * 512 + lane * 2) = v;
  }
  const int thalf = lane >> 5;
  const int c4 = (lane & 31) * 4;
#pragma unroll
  for (int i = 0; i < NTAB / 2; ++i) {
    const int t = 2 * i + thalf;
    const f32x4 v = *(const f32x4*)(emb + ((size_t)t * NR + idxs[t]) * 128 + c4);
    half4 h;
#pragma unroll
    for (int j = 0; j < 4; ++j) h[j] = (h16)v[j];
    *(half4*)&T[wv][1 + t][c4] = h;
  }

  __syncthreads();

  f32x4 acc00 = {}, acc10 = {}, acc11 = {};
  const int l15 = lane & 15;
  const int kq = lane >> 4;
#pragma unroll
  for (int kk = 0; kk < 4; ++kk) {
    const int ko = kk * 32 + kq * 8;
    half8 a0 = *(const half8*)&T[wv][l15][ko];
    half8 a1 = *(const half8*)&T[wv][16 + l15][ko];
    acc00 = __builtin_amdgcn_mfma_f32_16x16x32_f16(a0, a0, acc00, 0, 0, 0);
    acc10 = __builtin_amdgcn_mfma_f32_16x16x32_f16(a1, a0, acc10, 0, 0, 0);
    acc11 = __builtin_amdgcn_mfma_f32_16x16x32_f16(a1, a1, acc11, 0, 0, 0);
  }
  h16* zr = z + b * 512 + 128;
#pragma unroll
  for (int ri = 0; ri < 4; ++ri) {
    int i0 = kq * 4 + ri;
    int i1 = 16 + i0;
    if (l15 < i0) zr[i0 * (i0 - 1) / 2 + l15] = (h16)acc00[ri];
    if (i1 < 27) {
      zr[i1 * (i1 - 1) / 2 + l15] = (h16)acc10[ri];
      int j1 = 16 + l15;
      if (j1 < i1) zr[i1 * (i1 - 1) / 2 + j1] = (h16)acc11[ri];
    }
  }
}

extern "C" void kernel_launch(void* const* d_in, const int* in_sizes, int n_in,
                              void* d_out, int out_size, void* d_ws, size_t ws_size,
                              hipStream_t stream) {
  const float* dense_x = (const float*)d_in[0];
  const int* lSi = (const int*)d_in[2];
  const float* emb = (const float*)d_in[3];
  const float* bw0 = (const float*)d_in[4];
  const float* bb0 = (const float*)d_in[5];
  const float* bw1 = (const float*)d_in[6];
  const float* bb1 = (const float*)d_in[7];
  const float* bw2 = (const float*)d_in[8];
  const float* bb2 = (const float*)d_in[9];
  const float* tw0 = (const float*)d_in[10];
  const float* tb0 = (const float*)d_in[11];
  const float* tw1 = (const float*)d_in[12];
  const float* tb1 = (const float*)d_in[13];
  const float* tw2 = (const float*)d_in[14];
  const float* tb2 = (const float*)d_in[15];
  const float* tw3 = (const float*)d_in[16];
  const float* tb3 = (const float*)d_in[17];
  const float* tw4 = (const float*)d_in[18];
  const float* tb4 = (const float*)d_in[19];
  float* out = (float*)d_out;

  char* ws = (char*)d_ws;
  const size_t MB = (size_t)1 << 20;
  h16* Y0 = (h16*)(ws + 0 * MB);    // [B,512]   16MB   (dead after mid_k)
  h16* Xc = (h16*)(ws + 24 * MB);   // [B,128]    4MB   (dead after interact)
  h16* Zz = (h16*)(ws + 32 * MB);   // [B,512]   16MB   (dead after T0)
  h16* U0 = (h16*)(ws + 48 * MB);   // [B,1024]  32MB   (dead after T1)
  h16* U1 = (h16*)(ws + 0 * MB);    // [B,1024]  32MB   reuses Y0
  h16* U2 = (h16*)(ws + 32 * MB);   // [B,512]   16MB   reuses Zz
  float* partial = (float*)(ws + 48 * MB);  // [4,B] 256KB, reuses U0
  h16* w1p = (h16*)(ws + 80 * MB);  // fp16 weights, contiguous segments
  h16* w2p = w1p + 256 * 512;
  h16* t0p = w2p + 128 * 256;
  h16* t1p = t0p + 1024 * 512;
  h16* t2p = t1p + 1024 * 1024;
  h16* t3p = t2p + 512 * 1024;
  (void)in_sizes; (void)n_in; (void)out_size; (void)ws_size;

  cvt_bot0_k<<<9344 + 32768, 256, 0, stream>>>(bw1, bw2, tw0, tw1, tw2, tw3,
                                               w1p, dense_x, bw0, bb0, Y0);
  mid_k<<<256, 256, 0, stream>>>(Y0, w1p, bb1, w2p, bb2, Xc);
  interact_k<<<NB / 4, 256, 0, stream>>>(Xc, emb, lSi, Zz);
  gemm_wd<3><<<64 * 8, 256, 0, stream>>>(Zz, t0p, tb0, U0, 1024, 512);
  gemm_wd<3><<<64 * 8, 256, 0, stream>>>(U0, t1p, tb1, U1, 1024, 1024);
  gemm_wd<2><<<64 * 4, 256, 0, stream>>>(U1, t2p, tb2, U2, 512, 1024);
  gemm_t3f<<<128 * 2, 256, 0, stream>>>(U2, t3p, tb3, tw4, partial);
  sig_k<<<NB / 256, 256, 0, stream>>>(partial, tb4, out);
}

// Round 14
// 185.849 us; speedup vs baseline: 1.1132x; 1.1132x over previous
//
#include <hip/hip_runtime.h>
#include <cstdint>
#include <cstddef>

typedef _Float16 h16;
typedef __attribute__((ext_vector_type(8))) _Float16 half8;
typedef __attribute__((ext_vector_type(4))) _Float16 half4;
typedef __attribute__((ext_vector_type(2))) _Float16 half2v;
typedef __attribute__((ext_vector_type(4))) float f32x4;
typedef __attribute__((ext_vector_type(2))) float f32x2;

#define NB 16384
#define NTAB 26
#define NR 100000

__device__ __forceinline__ void gload16(const void* g, void* l) {
  __builtin_amdgcn_global_load_lds(
      (const __attribute__((address_space(1))) unsigned int*)g,
      (__attribute__((address_space(3))) unsigned int*)l, 16, 0, 0);
}

// ---- fused: f32->fp16 weight conversion (blocks 0..9343) + bottom layer 0
// (blocks 9344..9855, weight-stationary): Y[B,512] = relu(x @ W0^T + b0).
// bot0: 32 rows/block; thread owns cols {tid, tid+256} with W0 in 26 regs;
// x rows staged in LDS (wave-uniform broadcast reads); coalesced Y stores.
// Global traffic: x 852KB + W0 26KB/block (L2) + Y 16MB (vs ~870MB before).
__global__ __launch_bounds__(256) void cvt_bot0_k(
    const float* __restrict__ s0, const float* __restrict__ s1,
    const float* __restrict__ s2, const float* __restrict__ s3,
    const float* __restrict__ s4, const float* __restrict__ s5,
    h16* __restrict__ dst, const float* __restrict__ x,
    const float* __restrict__ W0, const float* __restrict__ b0,
    h16* __restrict__ Y) {
  __shared__ float xs[32][14];
  int b = blockIdx.x;
  if (b >= 9344) {
    const int bb = b - 9344;  // 0..511
    const int row0 = bb * 32;
    const int tid = threadIdx.x;
    for (int i = tid; i < 32 * 13; i += 256) {
      int r = i / 13, k = i - r * 13;
      xs[r][k] = x[(size_t)(row0 + r) * 13 + k];
    }
    float w0[13], w1[13];
#pragma unroll
    for (int k = 0; k < 13; ++k) {
      w0[k] = W0[tid * 13 + k];
      w1[k] = W0[(tid + 256) * 13 + k];
    }
    const float bz0 = b0[tid], bz1 = b0[tid + 256];
    __syncthreads();
    for (int r = 0; r < 32; ++r) {
      float a0 = bz0, a1 = bz1;
#pragma unroll
      for (int k = 0; k < 13; ++k) {
        const float xv = xs[r][k];
        a0 += xv * w0[k];
        a1 += xv * w1[k];
      }
      Y[(size_t)(row0 + r) * 512 + tid] = (h16)fmaxf(a0, 0.f);
      Y[(size_t)(row0 + r) * 512 + tid + 256] = (h16)fmaxf(a1, 0.f);
    }
    return;
  }
  const float* src; int K, kl, i0; size_t doff;
  if (b < 512)       { src=s0; K=512;  kl=9;  i0=(b-0)*256;    doff=0; }
  else if (b < 640)  { src=s1; K=256;  kl=8;  i0=(b-512)*256;  doff=131072; }
  else if (b < 2688) { src=s2; K=479;  kl=9;  i0=(b-640)*256;  doff=163840; }
  else if (b < 6784) { src=s3; K=1024; kl=10; i0=(b-2688)*256; doff=688128; }
  else if (b < 8832) { src=s4; K=1024; kl=10; i0=(b-6784)*256; doff=1736704; }
  else               { src=s5; K=512;  kl=9;  i0=(b-8832)*256; doff=2260992; }
  int i = i0 + threadIdx.x;
  int n = i >> kl, k = i & ((1 << kl) - 1);
  dst[doff + i] = (k < K) ? (h16)src[(size_t)n * K + k] : (h16)0.f;
}

// ---- fused mid MLP (R12): Xc = relu(relu(Y0 @ W1^T + b1) @ W2^T + b2).
__global__ __launch_bounds__(256, 2) void mid_k(
    const h16* __restrict__ Y0, const h16* __restrict__ W1,
    const float* __restrict__ b1, const h16* __restrict__ W2,
    const float* __restrict__ b2, h16* __restrict__ Xc) {
  __shared__ __align__(16) h16 Sa[64 * 64];
  __shared__ __align__(16) h16 Sb[256 * 64];
  __shared__ __align__(16) h16 Y1[64 * 264];
  const int tid = threadIdx.x;
  const int lane = tid & 63;
  const int w = tid >> 6;
  const int l15 = lane & 15;
  const int kq = lane >> 4;
  const int l7 = lane & 7;
  const int lr8 = lane >> 3;
  const size_t row0 = (size_t)blockIdx.x * 64;

  const int sch = (lane & 7) ^ lr8;
  const h16* gA = Y0 + (row0 + w * 16 + lr8) * 512 + sch * 8;
  const h16* gB = W1 + ((size_t)w * 64 + lr8) * 512 + sch * 8;

  f32x4 acc[4][4] = {};
  for (int t = 0; t < 8; ++t) {
    const int k0 = t * 64;
#pragma unroll
    for (int i = 0; i < 2; ++i)
      gload16(gA + (size_t)i * 8 * 512 + k0, Sa + w * 1024 + i * 512);
#pragma unroll
    for (int i = 0; i < 8; ++i)
      gload16(gB + (size_t)i * 8 * 512 + k0, Sb + w * 4096 + i * 512);
    __syncthreads();
#pragma unroll
    for (int kk = 0; kk < 2; ++kk) {
      const int kb = kk * 4 + kq;
      half8 a[4], bfr[4];
#pragma unroll
      for (int mi = 0; mi < 4; ++mi)
        a[mi] = *(const half8*)&Sa[(mi * 16 + l15) * 64 + ((kb ^ l7) << 3)];
#pragma unroll
      for (int ni = 0; ni < 4; ++ni)
        bfr[ni] = *(const half8*)&Sb[(w * 64 + ni * 16 + l15) * 64 + ((kb ^ l7) << 3)];
#pragma unroll
      for (int mi = 0; mi < 4; ++mi)
#pragma unroll
        for (int ni = 0; ni < 4; ++ni)
          acc[mi][ni] = __builtin_amdgcn_mfma_f32_16x16x32_f16(bfr[ni], a[mi], acc[mi][ni], 0, 0, 0);
    }
    __syncthreads();
  }

#pragma unroll
  for (int mi = 0; mi < 4; ++mi) {
    const int row = mi * 16 + l15;
#pragma unroll
    for (int ni = 0; ni < 4; ++ni) {
      const int col = w * 64 + ni * 16 + kq * 4;
      const f32x4 bv = *(const f32x4*)&b1[col];
      half4 h;
#pragma unroll
      for (int ri = 0; ri < 4; ++ri)
        h[ri] = (h16)fmaxf(acc[mi][ni][ri] + bv[ri], 0.f);
      *(half4*)&Y1[row * 264 + col] = h;
    }
  }
  __syncthreads();

  f32x4 acc2[4][2] = {};
  for (int ks = 0; ks < 8; ++ks) {
    half8 av[4], bv[2];
#pragma unroll
    for (int mi = 0; mi < 4; ++mi)
      av[mi] = *(const half8*)&Y1[(mi * 16 + l15) * 264 + ks * 32 + kq * 8];
#pragma unroll
    for (int nf = 0; nf < 2; ++nf) {
      const int col = (w * 2 + nf) * 16 + l15;
      bv[nf] = *(const half8*)&W2[(size_t)col * 256 + ks * 32 + kq * 8];
    }
#pragma unroll
    for (int mi = 0; mi < 4; ++mi)
#pragma unroll
      for (int nf = 0; nf < 2; ++nf)
        acc2[mi][nf] = __builtin_amdgcn_mfma_f32_16x16x32_f16(bv[nf], av[mi], acc2[mi][nf], 0, 0, 0);
  }
#pragma unroll
  for (int mi = 0; mi < 4; ++mi) {
    const size_t row = row0 + mi * 16 + l15;
#pragma unroll
    for (int nf = 0; nf < 2; ++nf) {
      const int col = (w * 2 + nf) * 16 + kq * 4;
      const f32x4 bv = *(const f32x4*)&b2[col];
      half4 h;
#pragma unroll
      for (int ri = 0; ri < 4; ++ri)
        h[ri] = (h16)fmaxf(acc2[mi][nf][ri] + bv[ri], 0.f);
      *(half4*)&Xc[row * 128 + col] = h;
    }
  }
}

// ---- 128x128-tile SINGLE-buffered fp16 MFMA GEMM (R12 best).
// 4 waves (2x2 of 64x64), BK=64, 32KB LDS, 4 blocks/CU. XCD-aware decode.
template <int GYL>
__global__ __launch_bounds__(256, 4) void gemm_sb(
    const h16* __restrict__ A, const h16* __restrict__ W,
    const float* __restrict__ bias, h16* __restrict__ C, int N, int K) {
  __shared__ __align__(16) h16 As[128 * 64];
  __shared__ __align__(16) h16 Bs[128 * 64];
  const int b = blockIdx.x;
  const int c8 = b & 7;
  const int q = b >> 3;
  const int jcol = q & ((1 << GYL) - 1);
  const int krow = ((q >> GYL) << 3) | c8;
  const int tid = threadIdx.x;
  const int lane = tid & 63;
  const int wave = tid >> 6;
  const int wm = wave >> 1, wn = wave & 1;
  const size_t row0 = (size_t)krow * 128;
  const size_t col0 = (size_t)jcol * 128;
  const int lr = lane >> 3;
  const int swzc = (((lane & 7) ^ lr) << 3);
  const int l15 = lane & 15;
  const int kq = lane >> 4;
  const int l7 = lane & 7;
  const int nt = K >> 6;

  const h16* ga = A + (row0 + wave * 32 + lr) * (size_t)K + swzc;
  const h16* gb = W + (col0 + wave * 32 + lr) * (size_t)K + swzc;

  f32x4 acc[4][4] = {};

  for (int t = 0; t < nt; ++t) {
    const int k0 = t << 6;
    h16* la = As + wave * 2048;
    h16* lb = Bs + wave * 2048;
#pragma unroll
    for (int i = 0; i < 4; ++i) {
      gload16(ga + (size_t)i * 8 * K + k0, la + i * 512);
      gload16(gb + (size_t)i * 8 * K + k0, lb + i * 512);
    }
    __syncthreads();
#pragma unroll
    for (int kk = 0; kk < 2; ++kk) {
      half8 a[4], bfr[4];
      const int kb = kk * 4 + kq;
#pragma unroll
      for (int mi = 0; mi < 4; ++mi)
        a[mi] = *(const half8*)&As[(wm * 64 + mi * 16 + l15) * 64 + ((kb ^ l7) << 3)];
#pragma unroll
      for (int ni = 0; ni < 4; ++ni)
        bfr[ni] = *(const half8*)&Bs[(wn * 64 + ni * 16 + l15) * 64 + ((kb ^ l7) << 3)];
#pragma unroll
      for (int mi = 0; mi < 4; ++mi)
#pragma unroll
        for (int ni = 0; ni < 4; ++ni)
          acc[mi][ni] = __builtin_amdgcn_mfma_f32_16x16x32_f16(a[mi], bfr[ni], acc[mi][ni], 0, 0, 0);
    }
    __syncthreads();
  }

#pragma unroll
  for (int mi = 0; mi < 4; ++mi)
#pragma unroll
    for (int ni = 0; ni < 4; ++ni) {
      const size_t col = col0 + wn * 64 + ni * 16 + l15;
      const float bv = bias[col];
#pragma unroll
      for (int ri = 0; ri < 4; ++ri) {
        const size_t row = row0 + wm * 64 + mi * 16 + kq * 4 + ri;
        float v = acc[mi][ni][ri] + bv;
        C[row * N + col] = (h16)fmaxf(v, 0.f);
      }
    }
}

// ---- T3 + top4 fused, single-buffered (N=256, K=512) (R11/R12).
__global__ __launch_bounds__(256, 4) void gemm_t3f(
    const h16* __restrict__ A, const h16* __restrict__ W,
    const float* __restrict__ bias, const float* __restrict__ w4,
    float* __restrict__ partial) {
  const int K = 512;
  __shared__ __align__(16) h16 As[128 * 64];
  __shared__ __align__(16) h16 Bs[128 * 64];
  const int b = blockIdx.x;
  const int c8 = b & 7;
  const int q = b >> 3;
  const int jcol = q & 1;
  const int krow = ((q >> 1) << 3) | c8;
  const int tid = threadIdx.x;
  const int lane = tid & 63;
  const int wave = tid >> 6;
  const int wm = wave >> 1, wn = wave & 1;
  const size_t row0 = (size_t)krow * 128;
  const size_t col0 = (size_t)jcol * 128;
  const int lr = lane >> 3;
  const int swzc = (((lane & 7) ^ lr) << 3);
  const int l15 = lane & 15;
  const int kq = lane >> 4;
  const int l7 = lane & 7;
  const int nt = K >> 6;

  const h16* ga = A + (row0 + wave * 32 + lr) * (size_t)K + swzc;
  const h16* gb = W + (col0 + wave * 32 + lr) * (size_t)K + swzc;

  f32x4 acc[4][4] = {};

  for (int t = 0; t < nt; ++t) {
    const int k0 = t << 6;
    h16* la = As + wave * 2048;
    h16* lb = Bs + wave * 2048;
#pragma unroll
    for (int i = 0; i < 4; ++i) {
      gload16(ga + (size_t)i * 8 * K + k0, la + i * 512);
      gload16(gb + (size_t)i * 8 * K + k0, lb + i * 512);
    }
    __syncthreads();
#pragma unroll
    for (int kk = 0; kk < 2; ++kk) {
      half8 a[4], bfr[4];
      const int kb = kk * 4 + kq;
#pragma unroll
      for (int mi = 0; mi < 4; ++mi)
        a[mi] = *(const half8*)&As[(wm * 64 + mi * 16 + l15) * 64 + ((kb ^ l7) << 3)];
#pragma unroll
      for (int ni = 0; ni < 4; ++ni)
        bfr[ni] = *(const half8*)&Bs[(wn * 64 + ni * 16 + l15) * 64 + ((kb ^ l7) << 3)];
#pragma unroll
      for (int mi = 0; mi < 4; ++mi)
#pragma unroll
        for (int ni = 0; ni < 4; ++ni)
          acc[mi][ni] = __builtin_amdgcn_mfma_f32_16x16x32_f16(a[mi], bfr[ni], acc[mi][ni], 0, 0, 0);
    }
    __syncthreads();
  }

  const int slot = jcol * 2 + wn;
#pragma unroll
  for (int mi = 0; mi < 4; ++mi) {
    float s[4] = {0.f, 0.f, 0.f, 0.f};
#pragma unroll
    for (int ni = 0; ni < 4; ++ni) {
      const size_t col = col0 + wn * 64 + ni * 16 + l15;
      const float bv = bias[col];
      const float wv = w4[col];
#pragma unroll
      for (int ri = 0; ri < 4; ++ri)
        s[ri] += fmaxf(acc[mi][ni][ri] + bv, 0.f) * wv;
    }
#pragma unroll
    for (int ri = 0; ri < 4; ++ri) {
      float v = s[ri];
      v += __shfl_xor(v, 1);
      v += __shfl_xor(v, 2);
      v += __shfl_xor(v, 4);
      v += __shfl_xor(v, 8);
      if (l15 == 0) {
        const size_t row = row0 + wm * 64 + mi * 16 + kq * 4 + ri;
        partial[(size_t)slot * NB + row] = v;
      }
    }
  }
}

// ---- final: out[r] = sigmoid(sum of 4 partials + tb4)
__global__ __launch_bounds__(256) void sig_k(
    const float* __restrict__ partial, const float* __restrict__ bias,
    float* __restrict__ out) {
  int r = blockIdx.x * 256 + threadIdx.x;
  float v = partial[r] + partial[NB + r] + partial[2 * NB + r] +
            partial[3 * NB + r] + bias[0];
  out[r] = 1.f / (1.f + expf(-v));
}

// ---- fused embedding gather + interaction (R9/R11).
__global__ __launch_bounds__(256) void interact_k(
    const h16* __restrict__ X, const float* __restrict__ emb,
    const int* __restrict__ lSi, h16* __restrict__ z) {
  __shared__ __align__(16) h16 T[4][32][136];
  const int lane = threadIdx.x & 63;
  const int wv = threadIdx.x >> 6;
  const size_t b = (size_t)blockIdx.x * 4 + wv;

  int idxs[NTAB];
#pragma unroll
  for (int t = 0; t < NTAB; ++t) idxs[t] = lSi[t * NB + (int)b];

  for (int i = lane; i < 5 * 128; i += 64)
    T[wv][27 + (i >> 7)][i & 127] = (h16)0.f;

  {
    half2v v = *(const half2v*)(X + b * 128 + lane * 2);
    *(half2v*)&T[wv][0][lane * 2] = v;
    *(half2v*)(z + b * 512 + lane * 2) = v;
  }
  const int thalf = lane >> 5;
  const int c4 = (lane & 31) * 4;
#pragma unroll
  for (int i = 0; i < NTAB / 2; ++i) {
    const int t = 2 * i + thalf;
    const f32x4 v = *(const f32x4*)(emb + ((size_t)t * NR + idxs[t]) * 128 + c4);
    half4 h;
#pragma unroll
    for (int j = 0; j < 4; ++j) h[j] = (h16)v[j];
    *(half4*)&T[wv][1 + t][c4] = h;
  }

  __syncthreads();

  f32x4 acc00 = {}, acc10 = {}, acc11 = {};
  const int l15 = lane & 15;
  const int kq = lane >> 4;
#pragma unroll
  for (int kk = 0; kk < 4; ++kk) {
    const int ko = kk * 32 + kq * 8;
    half8 a0 = *(const half8*)&T[wv][l15][ko];
    half8 a1 = *(const half8*)&T[wv][16 + l15][ko];
    acc00 = __builtin_amdgcn_mfma_f32_16x16x32_f16(a0, a0, acc00, 0, 0, 0);
    acc10 = __builtin_amdgcn_mfma_f32_16x16x32_f16(a1, a0, acc10, 0, 0, 0);
    acc11 = __builtin_amdgcn_mfma_f32_16x16x32_f16(a1, a1, acc11, 0, 0, 0);
  }
  h16* zr = z + b * 512 + 128;
#pragma unroll
  for (int ri = 0; ri < 4; ++ri) {
    int i0 = kq * 4 + ri;
    int i1 = 16 + i0;
    if (l15 < i0) zr[i0 * (i0 - 1) / 2 + l15] = (h16)acc00[ri];
    if (i1 < 27) {
      zr[i1 * (i1 - 1) / 2 + l15] = (h16)acc10[ri];
      int j1 = 16 + l15;
      if (j1 < i1) zr[i1 * (i1 - 1) / 2 + j1] = (h16)acc11[ri];
    }
  }
}

extern "C" void kernel_launch(void* const* d_in, const int* in_sizes, int n_in,
                              void* d_out, int out_size, void* d_ws, size_t ws_size,
                              hipStream_t stream) {
  const float* dense_x = (const float*)d_in[0];
  const int* lSi = (const int*)d_in[2];
  const float* emb = (const float*)d_in[3];
  const float* bw0 = (const float*)d_in[4];
  const float* bb0 = (const float*)d_in[5];
  const float* bw1 = (const float*)d_in[6];
  const float* bb1 = (const float*)d_in[7];
  const float* bw2 = (const float*)d_in[8];
  const float* bb2 = (const float*)d_in[9];
  const float* tw0 = (const float*)d_in[10];
  const float* tb0 = (const float*)d_in[11];
  const float* tw1 = (const float*)d_in[12];
  const float* tb1 = (const float*)d_in[13];
  const float* tw2 = (const float*)d_in[14];
  const float* tb2 = (const float*)d_in[15];
  const float* tw3 = (const float*)d_in[16];
  const float* tb3 = (const float*)d_in[17];
  const float* tw4 = (const float*)d_in[18];
  const float* tb4 = (const float*)d_in[19];
  float* out = (float*)d_out;

  char* ws = (char*)d_ws;
  const size_t MB = (size_t)1 << 20;
  h16* Y0 = (h16*)(ws + 0 * MB);    // [B,512]   16MB   (dead after mid_k)
  h16* Xc = (h16*)(ws + 24 * MB);   // [B,128]    4MB   (dead after interact)
  h16* Zz = (h16*)(ws + 32 * MB);   // [B,512]   16MB   (dead after T0)
  h16* U0 = (h16*)(ws + 48 * MB);   // [B,1024]  32MB   (dead after T1)
  h16* U1 = (h16*)(ws + 0 * MB);    // [B,1024]  32MB   reuses Y0
  h16* U2 = (h16*)(ws + 32 * MB);   // [B,512]   16MB   reuses Zz
  float* partial = (float*)(ws + 48 * MB);  // [4,B] 256KB, reuses U0
  h16* w1p = (h16*)(ws + 80 * MB);  // fp16 weights, contiguous segments
  h16* w2p = w1p + 256 * 512;
  h16* t0p = w2p + 128 * 256;
  h16* t1p = t0p + 1024 * 512;
  h16* t2p = t1p + 1024 * 1024;
  h16* t3p = t2p + 512 * 1024;
  (void)in_sizes; (void)n_in; (void)out_size; (void)ws_size;

  cvt_bot0_k<<<9344 + 512, 256, 0, stream>>>(bw1, bw2, tw0, tw1, tw2, tw3,
                                             w1p, dense_x, bw0, bb0, Y0);
  mid_k<<<256, 256, 0, stream>>>(Y0, w1p, bb1, w2p, bb2, Xc);
  interact_k<<<NB / 4, 256, 0, stream>>>(Xc, emb, lSi, Zz);
  gemm_sb<3><<<128 * 8, 256, 0, stream>>>(Zz, t0p, tb0, U0, 1024, 512);
  gemm_sb<3><<<128 * 8, 256, 0, stream>>>(U0, t1p, tb1, U1, 1024, 1024);
  gemm_sb<2><<<128 * 4, 256, 0, stream>>>(U1, t2p, tb2, U2, 512, 1024);
  gemm_t3f<<<128 * 2, 256, 0, stream>>>(U2, t3p, tb3, tw4, partial);
  sig_k<<<NB / 256, 256, 0, stream>>>(partial, tb4, out);
}

// Round 15
// 179.110 us; speedup vs baseline: 1.1551x; 1.0376x over previous
//
#include <hip/hip_runtime.h>
#include <cstdint>
#include <cstddef>

typedef _Float16 h16;
typedef __attribute__((ext_vector_type(8))) _Float16 half8;
typedef __attribute__((ext_vector_type(4))) _Float16 half4;
typedef __attribute__((ext_vector_type(2))) _Float16 half2v;
typedef __attribute__((ext_vector_type(4))) float f32x4;
typedef __attribute__((ext_vector_type(2))) float f32x2;

#define NB 16384
#define NTAB 26
#define NR 100000

__device__ __forceinline__ void gload16(const void* g, void* l) {
  __builtin_amdgcn_global_load_lds(
      (const __attribute__((address_space(1))) unsigned int*)g,
      (__attribute__((address_space(3))) unsigned int*)l, 16, 0, 0);
}

// ---- fused: f32->fp16 weight conversion (blocks 0..9343) + bottom layer 0
// (blocks 9344..9855, weight-stationary, R14: -20us vs naive).
__global__ __launch_bounds__(256) void cvt_bot0_k(
    const float* __restrict__ s0, const float* __restrict__ s1,
    const float* __restrict__ s2, const float* __restrict__ s3,
    const float* __restrict__ s4, const float* __restrict__ s5,
    h16* __restrict__ dst, const float* __restrict__ x,
    const float* __restrict__ W0, const float* __restrict__ b0,
    h16* __restrict__ Y) {
  __shared__ float xs[32][14];
  int b = blockIdx.x;
  if (b >= 9344) {
    const int bb = b - 9344;  // 0..511
    const int row0 = bb * 32;
    const int tid = threadIdx.x;
    for (int i = tid; i < 32 * 13; i += 256) {
      int r = i / 13, k = i - r * 13;
      xs[r][k] = x[(size_t)(row0 + r) * 13 + k];
    }
    float w0[13], w1[13];
#pragma unroll
    for (int k = 0; k < 13; ++k) {
      w0[k] = W0[tid * 13 + k];
      w1[k] = W0[(tid + 256) * 13 + k];
    }
    const float bz0 = b0[tid], bz1 = b0[tid + 256];
    __syncthreads();
    for (int r = 0; r < 32; ++r) {
      float a0 = bz0, a1 = bz1;
#pragma unroll
      for (int k = 0; k < 13; ++k) {
        const float xv = xs[r][k];
        a0 += xv * w0[k];
        a1 += xv * w1[k];
      }
      Y[(size_t)(row0 + r) * 512 + tid] = (h16)fmaxf(a0, 0.f);
      Y[(size_t)(row0 + r) * 512 + tid + 256] = (h16)fmaxf(a1, 0.f);
    }
    return;
  }
  const float* src; int K, kl, i0; size_t doff;
  if (b < 512)       { src=s0; K=512;  kl=9;  i0=(b-0)*256;    doff=0; }
  else if (b < 640)  { src=s1; K=256;  kl=8;  i0=(b-512)*256;  doff=131072; }
  else if (b < 2688) { src=s2; K=479;  kl=9;  i0=(b-640)*256;  doff=163840; }
  else if (b < 6784) { src=s3; K=1024; kl=10; i0=(b-2688)*256; doff=688128; }
  else if (b < 8832) { src=s4; K=1024; kl=10; i0=(b-6784)*256; doff=1736704; }
  else               { src=s5; K=512;  kl=9;  i0=(b-8832)*256; doff=2260992; }
  int i = i0 + threadIdx.x;
  int n = i >> kl, k = i & ((1 << kl) - 1);
  dst[doff + i] = (k < K) ? (h16)src[(size_t)n * K + k] : (h16)0.f;
}

// ---- fused mid MLP, 32-row blocks (grid 512, 2 blocks/CU):
// Xc = relu(relu(Y0 @ W1^T + b1) @ W2^T + b2).
// Phase 1: staged MFMA over K=512 (swapped-operand epilogue -> padded Y1
// LDS [32][264]); Phase 2: A from Y1 LDS, B direct from W2 global (L2-hot).
__global__ __launch_bounds__(256, 2) void mid_k(
    const h16* __restrict__ Y0, const h16* __restrict__ W1,
    const float* __restrict__ b1, const h16* __restrict__ W2,
    const float* __restrict__ b2, h16* __restrict__ Xc) {
  __shared__ __align__(16) h16 Sa[32 * 64];
  __shared__ __align__(16) h16 Sb[256 * 64];
  __shared__ __align__(16) h16 Y1[32 * 264];
  const int tid = threadIdx.x;
  const int lane = tid & 63;
  const int w = tid >> 6;
  const int l15 = lane & 15;
  const int kq = lane >> 4;
  const int l7 = lane & 7;
  const size_t row0 = (size_t)blockIdx.x * 32;

  const int srow = tid >> 3;                  // 0..31
  const int sch = (tid & 7) ^ (srow & 7);     // inverse-swizzled chunk
  const h16* gA = Y0 + (row0 + srow) * 512 + sch * 8;
  const h16* gB = W1 + (size_t)srow * 512 + sch * 8;

  f32x4 acc[2][4] = {};
  for (int t = 0; t < 8; ++t) {
    const int k0 = t * 64;
    gload16(gA + k0, Sa + tid * 8);
#pragma unroll
    for (int i = 0; i < 8; ++i)
      gload16(gB + (size_t)(i * 32) * 512 + k0, Sb + i * 2048 + tid * 8);
    __syncthreads();
#pragma unroll
    for (int kk = 0; kk < 2; ++kk) {
      const int kb = kk * 4 + kq;
      const int sl = (kb ^ l7) << 3;
      half8 a[2], bfr[4];
#pragma unroll
      for (int mi = 0; mi < 2; ++mi)
        a[mi] = *(const half8*)&Sa[(mi * 16 + l15) * 64 + sl];
#pragma unroll
      for (int ni = 0; ni < 4; ++ni)
        bfr[ni] = *(const half8*)&Sb[(w * 64 + ni * 16 + l15) * 64 + sl];
#pragma unroll
      for (int mi = 0; mi < 2; ++mi)
#pragma unroll
        for (int ni = 0; ni < 4; ++ni)
          acc[mi][ni] = __builtin_amdgcn_mfma_f32_16x16x32_f16(bfr[ni], a[mi], acc[mi][ni], 0, 0, 0);
    }
    __syncthreads();
  }

  // swapped-layout epilogue -> Y1 LDS (row = mi*16+l15, cols contiguous)
#pragma unroll
  for (int mi = 0; mi < 2; ++mi) {
    const int row = mi * 16 + l15;
#pragma unroll
    for (int ni = 0; ni < 4; ++ni) {
      const int col = w * 64 + ni * 16 + kq * 4;
      const f32x4 bv = *(const f32x4*)&b1[col];
      half4 h;
#pragma unroll
      for (int ri = 0; ri < 4; ++ri)
        h[ri] = (h16)fmaxf(acc[mi][ni][ri] + bv[ri], 0.f);
      *(half4*)&Y1[row * 264 + col] = h;
    }
  }
  __syncthreads();

  // phase 2: Xc[32][128], K=256. A from Y1 LDS (264 stride: 2-way free), B from W2 global.
  f32x4 acc2[2][2] = {};
  for (int ks = 0; ks < 8; ++ks) {
    half8 av[2], bv[2];
#pragma unroll
    for (int mi = 0; mi < 2; ++mi)
      av[mi] = *(const half8*)&Y1[(mi * 16 + l15) * 264 + ks * 32 + kq * 8];
#pragma unroll
    for (int nf = 0; nf < 2; ++nf) {
      const int col = (w * 2 + nf) * 16 + l15;
      bv[nf] = *(const half8*)&W2[(size_t)col * 256 + ks * 32 + kq * 8];
    }
#pragma unroll
    for (int mi = 0; mi < 2; ++mi)
#pragma unroll
      for (int nf = 0; nf < 2; ++nf)
        acc2[mi][nf] = __builtin_amdgcn_mfma_f32_16x16x32_f16(bv[nf], av[mi], acc2[mi][nf], 0, 0, 0);
  }
#pragma unroll
  for (int mi = 0; mi < 2; ++mi) {
    const size_t row = row0 + mi * 16 + l15;
#pragma unroll
    for (int nf = 0; nf < 2; ++nf) {
      const int col = (w * 2 + nf) * 16 + kq * 4;
      const f32x4 bv = *(const f32x4*)&b2[col];
      half4 h;
#pragma unroll
      for (int ri = 0; ri < 4; ++ri)
        h[ri] = (h16)fmaxf(acc2[mi][nf][ri] + bv[ri], 0.f);
      *(half4*)&Xc[row * 128 + col] = h;
    }
  }
}

// ---- 128x128-tile SINGLE-buffered fp16 MFMA GEMM (R12/R14 best).
// 4 waves (2x2 of 64x64), BK=64, 32KB LDS, 4 blocks/CU. XCD-aware decode.
template <int GYL>
__global__ __launch_bounds__(256, 4) void gemm_sb(
    const h16* __restrict__ A, const h16* __restrict__ W,
    const float* __restrict__ bias, h16* __restrict__ C, int N, int K) {
  __shared__ __align__(16) h16 As[128 * 64];
  __shared__ __align__(16) h16 Bs[128 * 64];
  const int b = blockIdx.x;
  const int c8 = b & 7;
  const int q = b >> 3;
  const int jcol = q & ((1 << GYL) - 1);
  const int krow = ((q >> GYL) << 3) | c8;
  const int tid = threadIdx.x;
  const int lane = tid & 63;
  const int wave = tid >> 6;
  const int wm = wave >> 1, wn = wave & 1;
  const size_t row0 = (size_t)krow * 128;
  const size_t col0 = (size_t)jcol * 128;
  const int lr = lane >> 3;
  const int swzc = (((lane & 7) ^ lr) << 3);
  const int l15 = lane & 15;
  const int kq = lane >> 4;
  const int l7 = lane & 7;
  const int nt = K >> 6;

  const h16* ga = A + (row0 + wave * 32 + lr) * (size_t)K + swzc;
  const h16* gb = W + (col0 + wave * 32 + lr) * (size_t)K + swzc;

  f32x4 acc[4][4] = {};

  for (int t = 0; t < nt; ++t) {
    const int k0 = t << 6;
    h16* la = As + wave * 2048;
    h16* lb = Bs + wave * 2048;
#pragma unroll
    for (int i = 0; i < 4; ++i) {
      gload16(ga + (size_t)i * 8 * K + k0, la + i * 512);
      gload16(gb + (size_t)i * 8 * K + k0, lb + i * 512);
    }
    __syncthreads();
#pragma unroll
    for (int kk = 0; kk < 2; ++kk) {
      half8 a[4], bfr[4];
      const int kb = kk * 4 + kq;
#pragma unroll
      for (int mi = 0; mi < 4; ++mi)
        a[mi] = *(const half8*)&As[(wm * 64 + mi * 16 + l15) * 64 + ((kb ^ l7) << 3)];
#pragma unroll
      for (int ni = 0; ni < 4; ++ni)
        bfr[ni] = *(const half8*)&Bs[(wn * 64 + ni * 16 + l15) * 64 + ((kb ^ l7) << 3)];
#pragma unroll
      for (int mi = 0; mi < 4; ++mi)
#pragma unroll
        for (int ni = 0; ni < 4; ++ni)
          acc[mi][ni] = __builtin_amdgcn_mfma_f32_16x16x32_f16(a[mi], bfr[ni], acc[mi][ni], 0, 0, 0);
    }
    __syncthreads();
  }

#pragma unroll
  for (int mi = 0; mi < 4; ++mi)
#pragma unroll
    for (int ni = 0; ni < 4; ++ni) {
      const size_t col = col0 + wn * 64 + ni * 16 + l15;
      const float bv = bias[col];
#pragma unroll
      for (int ri = 0; ri < 4; ++ri) {
        const size_t row = row0 + wm * 64 + mi * 16 + kq * 4 + ri;
        float v = acc[mi][ni][ri] + bv;
        C[row * N + col] = (h16)fmaxf(v, 0.f);
      }
    }
}

// ---- T3+top4+sigmoid fully fused: 32-row x full-N=256 blocks (grid 512,
// 2+ blocks/CU). Each wave computes 32x64 (acc[2][4]) over K=512; epilogue
// reduces relu(.)*tw4 over its 64 cols (shfl), block-reduces the 4 waves
// in LDS, applies sigmoid, writes out directly. No partial buffer, no sig_k.
__global__ __launch_bounds__(256, 4) void gemm_t3s(
    const h16* __restrict__ A, const h16* __restrict__ W,
    const float* __restrict__ bias, const float* __restrict__ w4,
    const float* __restrict__ b4, float* __restrict__ out) {
  const int K = 512;
  __shared__ __align__(16) h16 As[32 * 64];
  __shared__ __align__(16) h16 Bs[256 * 64];
  __shared__ float red[4][32];
  const int tid = threadIdx.x;
  const int lane = tid & 63;
  const int w = tid >> 6;
  const int l15 = lane & 15;
  const int kq = lane >> 4;
  const int l7 = lane & 7;
  const size_t row0 = (size_t)blockIdx.x * 32;

  const int srow = tid >> 3;
  const int sch = (tid & 7) ^ (srow & 7);
  const h16* gA = A + (row0 + srow) * (size_t)K + sch * 8;
  const h16* gB = W + (size_t)srow * K + sch * 8;

  f32x4 acc[2][4] = {};
  for (int t = 0; t < 8; ++t) {
    const int k0 = t * 64;
    gload16(gA + k0, As + tid * 8);
#pragma unroll
    for (int i = 0; i < 8; ++i)
      gload16(gB + (size_t)(i * 32) * K + k0, Bs + i * 2048 + tid * 8);
    __syncthreads();
#pragma unroll
    for (int kk = 0; kk < 2; ++kk) {
      const int kb = kk * 4 + kq;
      const int sl = (kb ^ l7) << 3;
      half8 a[2], bfr[4];
#pragma unroll
      for (int mi = 0; mi < 2; ++mi)
        a[mi] = *(const half8*)&As[(mi * 16 + l15) * 64 + sl];
#pragma unroll
      for (int ni = 0; ni < 4; ++ni)
        bfr[ni] = *(const half8*)&Bs[(w * 64 + ni * 16 + l15) * 64 + sl];
#pragma unroll
      for (int mi = 0; mi < 2; ++mi)
#pragma unroll
        for (int ni = 0; ni < 4; ++ni)
          acc[mi][ni] = __builtin_amdgcn_mfma_f32_16x16x32_f16(a[mi], bfr[ni], acc[mi][ni], 0, 0, 0);
    }
    __syncthreads();
  }

  // per-wave: sum over this wave's 64 cols of relu(acc+tb3)*tw4
#pragma unroll
  for (int mi = 0; mi < 2; ++mi) {
    float s[4] = {0.f, 0.f, 0.f, 0.f};
#pragma unroll
    for (int ni = 0; ni < 4; ++ni) {
      const int col = w * 64 + ni * 16 + l15;
      const float bv = bias[col];
      const float wv = w4[col];
#pragma unroll
      for (int ri = 0; ri < 4; ++ri)
        s[ri] += fmaxf(acc[mi][ni][ri] + bv, 0.f) * wv;
    }
#pragma unroll
    for (int ri = 0; ri < 4; ++ri) {
      float v = s[ri];
      v += __shfl_xor(v, 1);
      v += __shfl_xor(v, 2);
      v += __shfl_xor(v, 4);
      v += __shfl_xor(v, 8);
      if (l15 == 0) red[w][mi * 16 + kq * 4 + ri] = v;
    }
  }
  __syncthreads();
  if (tid < 32) {
    float v = red[0][tid] + red[1][tid] + red[2][tid] + red[3][tid] + b4[0];
    out[row0 + tid] = 1.f / (1.f + expf(-v));
  }
}

// ---- fused embedding gather + interaction (R9/R11/R14).
__global__ __launch_bounds__(256) void interact_k(
    const h16* __restrict__ X, const float* __restrict__ emb,
    const int* __restrict__ lSi, h16* __restrict__ z) {
  __shared__ __align__(16) h16 T[4][32][136];
  const int lane = threadIdx.x & 63;
  const int wv = threadIdx.x >> 6;
  const size_t b = (size_t)blockIdx.x * 4 + wv;

  int idxs[NTAB];
#pragma unroll
  for (int t = 0; t < NTAB; ++t) idxs[t] = lSi[t * NB + (int)b];

  for (int i = lane; i < 5 * 128; i += 64)
    T[wv][27 + (i >> 7)][i & 127] = (h16)0.f;

  {
    half2v v = *(const half2v*)(X + b * 128 + lane * 2);
    *(half2v*)&T[wv][0][lane * 2] = v;
    *(half2v*)(z + b * 512 + lane * 2) = v;
  }
  const int thalf = lane >> 5;
  const int c4 = (lane & 31) * 4;
#pragma unroll
  for (int i = 0; i < NTAB / 2; ++i) {
    const int t = 2 * i + thalf;
    const f32x4 v = *(const f32x4*)(emb + ((size_t)t * NR + idxs[t]) * 128 + c4);
    half4 h;
#pragma unroll
    for (int j = 0; j < 4; ++j) h[j] = (h16)v[j];
    *(half4*)&T[wv][1 + t][c4] = h;
  }

  __syncthreads();

  f32x4 acc00 = {}, acc10 = {}, acc11 = {};
  const int l15 = lane & 15;
  const int kq = lane >> 4;
#pragma unroll
  for (int kk = 0; kk < 4; ++kk) {
    const int ko = kk * 32 + kq * 8;
    half8 a0 = *(const half8*)&T[wv][l15][ko];
    half8 a1 = *(const half8*)&T[wv][16 + l15][ko];
    acc00 = __builtin_amdgcn_mfma_f32_16x16x32_f16(a0, a0, acc00, 0, 0, 0);
    acc10 = __builtin_amdgcn_mfma_f32_16x16x32_f16(a1, a0, acc10, 0, 0, 0);
    acc11 = __builtin_amdgcn_mfma_f32_16x16x32_f16(a1, a1, acc11, 0, 0, 0);
  }
  h16* zr = z + b * 512 + 128;
#pragma unroll
  for (int ri = 0; ri < 4; ++ri) {
    int i0 = kq * 4 + ri;
    int i1 = 16 + i0;
    if (l15 < i0) zr[i0 * (i0 - 1) / 2 + l15] = (h16)acc00[ri];
    if (i1 < 27) {
      zr[i1 * (i1 - 1) / 2 + l15] = (h16)acc10[ri];
      int j1 = 16 + l15;
      if (j1 < i1) zr[i1 * (i1 - 1) / 2 + j1] = (h16)acc11[ri];
    }
  }
}

extern "C" void kernel_launch(void* const* d_in, const int* in_sizes, int n_in,
                              void* d_out, int out_size, void* d_ws, size_t ws_size,
                              hipStream_t stream) {
  const float* dense_x = (const float*)d_in[0];
  const int* lSi = (const int*)d_in[2];
  const float* emb = (const float*)d_in[3];
  const float* bw0 = (const float*)d_in[4];
  const float* bb0 = (const float*)d_in[5];
  const float* bw1 = (const float*)d_in[6];
  const float* bb1 = (const float*)d_in[7];
  const float* bw2 = (const float*)d_in[8];
  const float* bb2 = (const float*)d_in[9];
  const float* tw0 = (const float*)d_in[10];
  const float* tb0 = (const float*)d_in[11];
  const float* tw1 = (const float*)d_in[12];
  const float* tb1 = (const float*)d_in[13];
  const float* tw2 = (const float*)d_in[14];
  const float* tb2 = (const float*)d_in[15];
  const float* tw3 = (const float*)d_in[16];
  const float* tb3 = (const float*)d_in[17];
  const float* tw4 = (const float*)d_in[18];
  const float* tb4 = (const float*)d_in[19];
  float* out = (float*)d_out;

  char* ws = (char*)d_ws;
  const size_t MB = (size_t)1 << 20;
  h16* Y0 = (h16*)(ws + 0 * MB);    // [B,512]   16MB   (dead after mid_k)
  h16* Xc = (h16*)(ws + 24 * MB);   // [B,128]    4MB   (dead after interact)
  h16* Zz = (h16*)(ws + 32 * MB);   // [B,512]   16MB   (dead after T0)
  h16* U0 = (h16*)(ws + 48 * MB);   // [B,1024]  32MB   (dead after T1)
  h16* U1 = (h16*)(ws + 0 * MB);    // [B,1024]  32MB   reuses Y0
  h16* U2 = (h16*)(ws + 32 * MB);   // [B,512]   16MB   reuses Zz
  h16* w1p = (h16*)(ws + 80 * MB);  // fp16 weights, contiguous segments
  h16* w2p = w1p + 256 * 512;
  h16* t0p = w2p + 128 * 256;
  h16* t1p = t0p + 1024 * 512;
  h16* t2p = t1p + 1024 * 1024;
  h16* t3p = t2p + 512 * 1024;
  (void)in_sizes; (void)n_in; (void)out_size; (void)ws_size;

  cvt_bot0_k<<<9344 + 512, 256, 0, stream>>>(bw1, bw2, tw0, tw1, tw2, tw3,
                                             w1p, dense_x, bw0, bb0, Y0);
  mid_k<<<512, 256, 0, stream>>>(Y0, w1p, bb1, w2p, bb2, Xc);
  interact_k<<<NB / 4, 256, 0, stream>>>(Xc, emb, lSi, Zz);
  gemm_sb<3><<<128 * 8, 256, 0, stream>>>(Zz, t0p, tb0, U0, 1024, 512);
  gemm_sb<3><<<128 * 8, 256, 0, stream>>>(U0, t1p, tb1, U1, 1024, 1024);
  gemm_sb<2><<<128 * 4, 256, 0, stream>>>(U1, t2p, tb2, U2, 512, 1024);
  gemm_t3s<<<512, 256, 0, stream>>>(U2, t3p, tb3, tw4, tb4, out);
}